// Round 1
// baseline (549.023 us; speedup 1.0000x reference)
//
#include <hip/hip_runtime.h>
#include <hip/hip_bf16.h>

typedef short v8s __attribute__((ext_vector_type(8)));
typedef float v4f __attribute__((ext_vector_type(4)));

static constexpr int BB = 8;
static constexpr int SS = 2048;
static constexpr int EE = 512;

enum { EPI_BF16 = 0, EPI_BF16_T = 1, EPI_MASK = 2, EPI_FINAL = 3 };

struct EpiParams {
  float scale;
  const unsigned char* mask;
  unsigned long long maskStrideZ;
  int mask_ld;
  const float* bias;
  const __hip_bfloat16* resid;
  int resid_ld;
  int trans_ld;
};

__device__ __forceinline__ void load16(const float* __restrict__ p, __hip_bfloat16* h) {
  const float4* p4 = (const float4*)p;
#pragma unroll
  for (int i = 0; i < 4; ++i) {
    float4 f = p4[i];
    h[i * 4 + 0] = __float2bfloat16(f.x);
    h[i * 4 + 1] = __float2bfloat16(f.y);
    h[i * 4 + 2] = __float2bfloat16(f.z);
    h[i * 4 + 3] = __float2bfloat16(f.w);
  }
}

__device__ __forceinline__ void load16(const __hip_bfloat16* __restrict__ p, __hip_bfloat16* h) {
  const uint4* p4 = (const uint4*)p;
  uint4 a = p4[0], b = p4[1];
  ((uint4*)h)[0] = a;
  ((uint4*)h)[1] = b;
}

// C = A @ B^T, A[M,K] (lda), B[N,K] (ldb). 128x128 tile, BK=32, 256 threads,
// 4 waves in 2x2, each wave 64x64 via 4x4 of 16x16x32 bf16 MFMA.
template <typename TA, typename TB, int EPI>
__global__ __launch_bounds__(256, 2) void gemm_bt(
    const TA* __restrict__ Ag, const TB* __restrict__ Bg, void* __restrict__ Cg,
    int M, int N, int K, int lda, int ldb, int ldc,
    unsigned long long strideAz, unsigned long long strideBz, unsigned long long strideCz,
    EpiParams ep) {
  // stride 40 (=32+8) keeps ds_read_b128 bank aliasing at 2-way (free) and 16B alignment
  __shared__ __hip_bfloat16 As[128][40];
  __shared__ __hip_bfloat16 Bs[128][40];

  const int tid = threadIdx.x;
  const int lane = tid & 63;
  const int wave = tid >> 6;
  const int wr = wave >> 1;  // wave row 0..1
  const int wc = wave & 1;   // wave col 0..1
  const int z = blockIdx.z;
  const int m0 = blockIdx.y * 128;
  const int n0 = blockIdx.x * 128;

  Ag += (unsigned long long)z * strideAz;
  Bg += (unsigned long long)z * strideBz;

  v4f acc[4][4];
  const v4f vzero = {0.f, 0.f, 0.f, 0.f};
#pragma unroll
  for (int i = 0; i < 4; ++i)
#pragma unroll
    for (int j = 0; j < 4; ++j) acc[i][j] = vzero;

  const int srow = tid >> 1;          // 0..127
  const int shalf = (tid & 1) * 16;   // 0 or 16

  const int fr = lane & 15;
  const int fk = (lane >> 4) * 8;

  for (int k0 = 0; k0 < K; k0 += 32) {
    __syncthreads();
    {
      alignas(16) __hip_bfloat16 h[16];
      const TA* src = Ag + (unsigned long long)(m0 + srow) * lda + (k0 + shalf);
      load16(src, h);
      uint4* d = (uint4*)&As[srow][shalf];
      d[0] = ((uint4*)h)[0];
      d[1] = ((uint4*)h)[1];
    }
    {
      alignas(16) __hip_bfloat16 h[16];
      const TB* src = Bg + (unsigned long long)(n0 + srow) * ldb + (k0 + shalf);
      load16(src, h);
      uint4* d = (uint4*)&Bs[srow][shalf];
      d[0] = ((uint4*)h)[0];
      d[1] = ((uint4*)h)[1];
    }
    __syncthreads();

    v8s a[4], b[4];
#pragma unroll
    for (int i = 0; i < 4; ++i) a[i] = *(const v8s*)&As[wr * 64 + i * 16 + fr][fk];
#pragma unroll
    for (int j = 0; j < 4; ++j) b[j] = *(const v8s*)&Bs[wc * 64 + j * 16 + fr][fk];
#pragma unroll
    for (int i = 0; i < 4; ++i)
#pragma unroll
      for (int j = 0; j < 4; ++j)
        acc[i][j] = __builtin_amdgcn_mfma_f32_16x16x32_bf16(a[i], b[j], acc[i][j], 0, 0, 0);
  }

  // Epilogue. C/D layout: col = lane&15, row = (lane>>4)*4 + reg  (m89/m91 verified)
  const int cf = lane & 15;
  const int rq = (lane >> 4) * 4;
  const int colBase = n0 + wc * 64;
  const int rowBase = m0 + wr * 64;

#pragma unroll
  for (int i = 0; i < 4; ++i) {
#pragma unroll
    for (int j = 0; j < 4; ++j) {
      const int col = colBase + j * 16 + cf;
      const int row0 = rowBase + i * 16 + rq;
      if constexpr (EPI == EPI_BF16) {
        __hip_bfloat16* C = (__hip_bfloat16*)Cg + (unsigned long long)z * strideCz;
#pragma unroll
        for (int r = 0; r < 4; ++r)
          C[(unsigned long long)(row0 + r) * ldc + col] = __float2bfloat16(acc[i][j][r]);
      } else if constexpr (EPI == EPI_BF16_T) {
        // store C^T: Cg[col * trans_ld + row], 4 consecutive rows -> 8B packed store
        __hip_bfloat16* C = (__hip_bfloat16*)Cg + (unsigned long long)z * strideCz;
        alignas(8) __hip_bfloat16 t4[4];
#pragma unroll
        for (int r = 0; r < 4; ++r) t4[r] = __float2bfloat16(acc[i][j][r]);
        *(ushort4*)&C[(unsigned long long)col * ep.trans_ld + row0] = *(ushort4*)t4;
      } else if constexpr (EPI == EPI_MASK) {
        __hip_bfloat16* C = (__hip_bfloat16*)Cg + (unsigned long long)z * strideCz;
        const unsigned char* mk = ep.mask + (unsigned long long)z * ep.maskStrideZ;
#pragma unroll
        for (int r = 0; r < 4; ++r) {
          float v = acc[i][j][r] * ep.scale;
          if (mk[(unsigned long long)(row0 + r) * ep.mask_ld + col]) v = -1e9f;
          C[(unsigned long long)(row0 + r) * ldc + col] = __float2bfloat16(v);
        }
      } else {  // EPI_FINAL: out = acc + bias[col] + resid[row,col], f32 store
        float* C = (float*)Cg + (unsigned long long)z * strideCz;
        const float bi = ep.bias[col];
#pragma unroll
        for (int r = 0; r < 4; ++r) {
          float v = acc[i][j][r] + bi +
                    __bfloat162float(ep.resid[(unsigned long long)(row0 + r) * ep.resid_ld + col]);
          C[(unsigned long long)(row0 + r) * ldc + col] = v;
        }
      }
    }
  }
}

// In-place row softmax over bf16 scores: one block (256 thr) per row of 2048.
__global__ __launch_bounds__(256) void softmax_rows(__hip_bfloat16* __restrict__ sc) {
  const unsigned long long row = blockIdx.x;
  __hip_bfloat16* p = sc + row * (unsigned long long)SS;
  const int tid = threadIdx.x;
  const int lane = tid & 63;
  const int wv = tid >> 6;

  alignas(16) __hip_bfloat16 hv[8];
  ((uint4*)hv)[0] = *(const uint4*)&p[tid * 8];

  float v[8];
  float m = -3.4e38f;
#pragma unroll
  for (int i = 0; i < 8; ++i) {
    v[i] = __bfloat162float(hv[i]);
    m = fmaxf(m, v[i]);
  }
#pragma unroll
  for (int off = 32; off >= 1; off >>= 1) m = fmaxf(m, __shfl_xor(m, off));

  __shared__ float redm[4];
  __shared__ float reds[4];
  if (lane == 0) redm[wv] = m;
  __syncthreads();
  m = fmaxf(fmaxf(redm[0], redm[1]), fmaxf(redm[2], redm[3]));

  float s = 0.f;
#pragma unroll
  for (int i = 0; i < 8; ++i) {
    v[i] = __expf(v[i] - m);
    s += v[i];
  }
#pragma unroll
  for (int off = 32; off >= 1; off >>= 1) s += __shfl_xor(s, off);
  if (lane == 0) reds[wv] = s;
  __syncthreads();
  s = reds[0] + reds[1] + reds[2] + reds[3];
  const float inv = 1.0f / s;

#pragma unroll
  for (int i = 0; i < 8; ++i) hv[i] = __float2bfloat16(v[i] * inv);
  *(uint4*)&p[tid * 8] = ((uint4*)hv)[0];
}

extern "C" void kernel_launch(void* const* d_in, const int* in_sizes, int n_in,
                              void* d_out, int out_size, void* d_ws, size_t ws_size,
                              hipStream_t stream) {
  const float* Q = (const float*)d_in[0];
  const float* K = (const float*)d_in[1];
  const unsigned char* mask = (const unsigned char*)d_in[2];  // numpy bool, 1 byte
  const float* Wq = (const float*)d_in[3];
  const float* Wk = (const float*)d_in[4];
  const float* Wv = (const float*)d_in[5];
  const float* Wp = (const float*)d_in[6];
  const float* bp = (const float*)d_in[7];
  float* out = (float*)d_out;

  char* ws = (char*)d_ws;
  const unsigned long long seg = (unsigned long long)BB * SS * EE * 2ull;  // 16 MiB
  __hip_bfloat16* qb = (__hip_bfloat16*)(ws + 0 * seg);  // [B*S, E]
  __hip_bfloat16* kb = (__hip_bfloat16*)(ws + 1 * seg);  // [B*S, E]
  __hip_bfloat16* vT = (__hip_bfloat16*)(ws + 2 * seg);  // [E, B*S] (v transposed)
  __hip_bfloat16* ob = (__hip_bfloat16*)(ws + 3 * seg);  // [B*S, E] attn output
  __hip_bfloat16* sc = (__hip_bfloat16*)(ws + 4 * seg);  // [B, S, S] scores->probs (4*seg)

  dim3 blk(256, 1, 1);
  EpiParams ep0{};  // zeroed

  // q = Q @ Wq^T ; k = K @ Wk^T    (bf16 out)
  gemm_bt<float, float, EPI_BF16><<<dim3(EE / 128, (BB * SS) / 128, 1), blk, 0, stream>>>(
      Q, Wq, qb, BB * SS, EE, EE, EE, EE, EE, 0ull, 0ull, 0ull, ep0);
  gemm_bt<float, float, EPI_BF16><<<dim3(EE / 128, (BB * SS) / 128, 1), blk, 0, stream>>>(
      K, Wk, kb, BB * SS, EE, EE, EE, EE, EE, 0ull, 0ull, 0ull, ep0);

  // v = K @ Wv^T, stored transposed as vT[e, b*S + s]
  EpiParams epv{};
  epv.trans_ld = BB * SS;
  gemm_bt<float, float, EPI_BF16_T><<<dim3(EE / 128, (BB * SS) / 128, 1), blk, 0, stream>>>(
      K, Wv, vT, BB * SS, EE, EE, EE, EE, EE, 0ull, 0ull, 0ull, epv);

  // scores[b] = (q_b @ k_b^T) * scale, masked -> bf16
  EpiParams eps{};
  eps.scale = 0.044194173824159216f;  // 512^-0.5
  eps.mask = mask;
  eps.maskStrideZ = (unsigned long long)SS * SS;
  eps.mask_ld = SS;
  gemm_bt<__hip_bfloat16, __hip_bfloat16, EPI_MASK>
      <<<dim3(SS / 128, SS / 128, BB), blk, 0, stream>>>(
          qb, kb, sc, SS, SS, EE, EE, EE, SS,
          (unsigned long long)SS * EE, (unsigned long long)SS * EE,
          (unsigned long long)SS * SS, eps);

  // softmax rows, in place
  softmax_rows<<<dim3(BB * SS, 1, 1), blk, 0, stream>>>(sc);

  // ob[b] = P_b @ v_b   (= P @ vT^T, B^T-form with ldb = B*S)
  gemm_bt<__hip_bfloat16, __hip_bfloat16, EPI_BF16>
      <<<dim3(EE / 128, SS / 128, BB), blk, 0, stream>>>(
          sc, vT, ob, SS, EE, SS, SS, BB * SS, EE,
          (unsigned long long)SS * SS, (unsigned long long)SS,
          (unsigned long long)SS * EE, ep0);

  // out = q + (ob @ Wp^T + bp)   (f32 out)
  EpiParams epf{};
  epf.bias = bp;
  epf.resid = qb;
  epf.resid_ld = EE;
  gemm_bt<__hip_bfloat16, float, EPI_FINAL><<<dim3(EE / 128, (BB * SS) / 128, 1), blk, 0, stream>>>(
      ob, Wp, out, BB * SS, EE, EE, EE, EE, EE, 0ull, 0ull, 0ull, epf);
}

// Round 2
// 482.243 us; speedup vs baseline: 1.1385x; 1.1385x over previous
//
#include <hip/hip_runtime.h>
#include <hip/hip_bf16.h>

typedef short v8s __attribute__((ext_vector_type(8)));
typedef float v4f __attribute__((ext_vector_type(4)));

static constexpr int BB = 8;
static constexpr int SS = 2048;
static constexpr int EE = 512;

enum { EPI_BF16 = 0, EPI_BF16_T = 1, EPI_MASK = 2, EPI_FINAL = 3 };

struct EpiParams {
  float scale;
  const unsigned char* mask;
  unsigned long long maskStrideZ;
  int mask_ld;
  const float* bias;
  const __hip_bfloat16* resid;
  int resid_ld;
  int trans_ld;
};

// Cast n (multiple of 8) f32 -> bf16, 8 elements/thread.
__global__ __launch_bounds__(256) void cast_f32_bf16(const float* __restrict__ x,
                                                     __hip_bfloat16* __restrict__ y, int n) {
  int i = (blockIdx.x * 256 + threadIdx.x) * 8;
  if (i >= n) return;
  float4 f0 = ((const float4*)(x + i))[0];
  float4 f1 = ((const float4*)(x + i))[1];
  alignas(16) __hip_bfloat16 h[8];
  h[0] = __float2bfloat16(f0.x); h[1] = __float2bfloat16(f0.y);
  h[2] = __float2bfloat16(f0.z); h[3] = __float2bfloat16(f0.w);
  h[4] = __float2bfloat16(f1.x); h[5] = __float2bfloat16(f1.y);
  h[6] = __float2bfloat16(f1.z); h[7] = __float2bfloat16(f1.w);
  *(uint4*)(y + i) = *(uint4*)h;
}

// Stage one 128x32 bf16 tile (8 KB) into LDS via global_load_lds width=16.
// Chunk c = row*4 + kc (16B each); wave covers chunks [(wave*2+t)*64, +64).
// LDS dest is wave-uniform base + lane*16 (m104/m108) -> layout is linear row-major.
__device__ __forceinline__ void stage_tile(const __hip_bfloat16* __restrict__ G,
                                           int row0, int ld, int k0,
                                           __hip_bfloat16* lds, int wave, int lane) {
#pragma unroll
  for (int t = 0; t < 2; ++t) {
    const int c = (wave * 2 + t) * 64 + lane;
    const int row = c >> 2;
    const int kc = c & 3;
    const __hip_bfloat16* g = G + (unsigned long long)(row0 + row) * ld + k0 + kc * 8;
    __builtin_amdgcn_global_load_lds(
        (const __attribute__((address_space(1))) void*)g,
        (__attribute__((address_space(3))) void*)(lds + (wave * 2 + t) * 512),
        16, 0, 0);
  }
}

// C = A @ B^T, A[M,K] (lda), B[N,K] (ldb), all bf16 in. 128x128 tile, BK=32,
// 256 threads = 4 waves in 2x2, each wave 64x64 via 4x4 of 16x16x32 bf16 MFMA.
// m97-structure: global_load_lds staging, unpadded [128][32] LDS tiles.
template <int EPI>
__global__ __launch_bounds__(256, 2) void gemm_bt(
    const __hip_bfloat16* __restrict__ Ag, const __hip_bfloat16* __restrict__ Bg,
    void* __restrict__ Cg, int M, int N, int K, int lda, int ldb, int ldc,
    unsigned long long strideAz, unsigned long long strideBz, unsigned long long strideCz,
    EpiParams ep) {
  __shared__ __hip_bfloat16 As[128 * 32];
  __shared__ __hip_bfloat16 Bs[128 * 32];

  const int tid = threadIdx.x;
  const int lane = tid & 63;
  const int wave = tid >> 6;
  const int wr = wave >> 1;
  const int wc = wave & 1;
  const int z = blockIdx.z;
  const int m0 = blockIdx.y * 128;
  const int n0 = blockIdx.x * 128;

  Ag += (unsigned long long)z * strideAz;
  Bg += (unsigned long long)z * strideBz;

  v4f acc[4][4];
  const v4f vzero = {0.f, 0.f, 0.f, 0.f};
#pragma unroll
  for (int i = 0; i < 4; ++i)
#pragma unroll
    for (int j = 0; j < 4; ++j) acc[i][j] = vzero;

  const int fr = lane & 15;
  const int fk = (lane >> 4) * 8;  // k-chunk within BK=32

  for (int k0 = 0; k0 < K; k0 += 32) {
    __syncthreads();  // previous iter's ds_reads done before overwrite
    stage_tile(Ag, m0, lda, k0, As, wave, lane);
    stage_tile(Bg, n0, ldb, k0, Bs, wave, lane);
    __syncthreads();  // drain vmcnt (compiler emits full waitcnt at barrier)

    v8s a[4], b[4];
#pragma unroll
    for (int i = 0; i < 4; ++i) a[i] = *(const v8s*)&As[(wr * 64 + i * 16 + fr) * 32 + fk];
#pragma unroll
    for (int j = 0; j < 4; ++j) b[j] = *(const v8s*)&Bs[(wc * 64 + j * 16 + fr) * 32 + fk];
#pragma unroll
    for (int i = 0; i < 4; ++i)
#pragma unroll
      for (int j = 0; j < 4; ++j)
        acc[i][j] = __builtin_amdgcn_mfma_f32_16x16x32_bf16(a[i], b[j], acc[i][j], 0, 0, 0);
  }

  // Epilogue. C/D layout: col = lane&15, row = (lane>>4)*4 + reg (m89/m91)
  const int cf = lane & 15;
  const int rq = (lane >> 4) * 4;
  const int colBase = n0 + wc * 64;
  const int rowBase = m0 + wr * 64;

#pragma unroll
  for (int i = 0; i < 4; ++i) {
#pragma unroll
    for (int j = 0; j < 4; ++j) {
      const int col = colBase + j * 16 + cf;
      const int row0 = rowBase + i * 16 + rq;
      if constexpr (EPI == EPI_BF16) {
        __hip_bfloat16* C = (__hip_bfloat16*)Cg + (unsigned long long)z * strideCz;
#pragma unroll
        for (int r = 0; r < 4; ++r)
          C[(unsigned long long)(row0 + r) * ldc + col] = __float2bfloat16(acc[i][j][r]);
      } else if constexpr (EPI == EPI_BF16_T) {
        // store C^T: 4 consecutive rows -> one 8B packed store
        __hip_bfloat16* C = (__hip_bfloat16*)Cg + (unsigned long long)z * strideCz;
        alignas(8) __hip_bfloat16 t4[4];
#pragma unroll
        for (int r = 0; r < 4; ++r) t4[r] = __float2bfloat16(acc[i][j][r]);
        *(ushort4*)&C[(unsigned long long)col * ep.trans_ld + row0] = *(ushort4*)t4;
      } else if constexpr (EPI == EPI_MASK) {
        __hip_bfloat16* C = (__hip_bfloat16*)Cg + (unsigned long long)z * strideCz;
        const unsigned char* mk = ep.mask + (unsigned long long)z * ep.maskStrideZ;
#pragma unroll
        for (int r = 0; r < 4; ++r) {
          float v = acc[i][j][r] * ep.scale;
          if (mk[(unsigned long long)(row0 + r) * ep.mask_ld + col]) v = -1e9f;
          C[(unsigned long long)(row0 + r) * ldc + col] = __float2bfloat16(v);
        }
      } else {  // EPI_FINAL: out = acc + bias[col] + resid[row,col], f32 store
        float* C = (float*)Cg + (unsigned long long)z * strideCz;
        const float bi = ep.bias[col];
#pragma unroll
        for (int r = 0; r < 4; ++r) {
          float v = acc[i][j][r] + bi +
                    __bfloat162float(ep.resid[(unsigned long long)(row0 + r) * ep.resid_ld + col]);
          C[(unsigned long long)(row0 + r) * ldc + col] = v;
        }
      }
    }
  }
}

// In-place row softmax over bf16 scores: one block (256 thr) per row of 2048.
__global__ __launch_bounds__(256) void softmax_rows(__hip_bfloat16* __restrict__ sc) {
  const unsigned long long row = blockIdx.x;
  __hip_bfloat16* p = sc + row * (unsigned long long)SS;
  const int tid = threadIdx.x;
  const int lane = tid & 63;
  const int wv = tid >> 6;

  alignas(16) __hip_bfloat16 hv[8];
  ((uint4*)hv)[0] = *(const uint4*)&p[tid * 8];

  float v[8];
  float m = -3.4e38f;
#pragma unroll
  for (int i = 0; i < 8; ++i) {
    v[i] = __bfloat162float(hv[i]);
    m = fmaxf(m, v[i]);
  }
#pragma unroll
  for (int off = 32; off >= 1; off >>= 1) m = fmaxf(m, __shfl_xor(m, off));

  __shared__ float redm[4];
  __shared__ float reds[4];
  if (lane == 0) redm[wv] = m;
  __syncthreads();
  m = fmaxf(fmaxf(redm[0], redm[1]), fmaxf(redm[2], redm[3]));

  float s = 0.f;
#pragma unroll
  for (int i = 0; i < 8; ++i) {
    v[i] = __expf(v[i] - m);
    s += v[i];
  }
#pragma unroll
  for (int off = 32; off >= 1; off >>= 1) s += __shfl_xor(s, off);
  if (lane == 0) reds[wv] = s;
  __syncthreads();
  s = reds[0] + reds[1] + reds[2] + reds[3];
  const float inv = 1.0f / s;

#pragma unroll
  for (int i = 0; i < 8; ++i) hv[i] = __float2bfloat16(v[i] * inv);
  *(uint4*)&p[tid * 8] = ((uint4*)hv)[0];
}

extern "C" void kernel_launch(void* const* d_in, const int* in_sizes, int n_in,
                              void* d_out, int out_size, void* d_ws, size_t ws_size,
                              hipStream_t stream) {
  const float* Q = (const float*)d_in[0];
  const float* K = (const float*)d_in[1];
  const unsigned char* mask = (const unsigned char*)d_in[2];  // numpy bool, 1 byte
  const float* Wq = (const float*)d_in[3];
  const float* Wk = (const float*)d_in[4];
  const float* Wv = (const float*)d_in[5];
  const float* Wp = (const float*)d_in[6];
  const float* bp = (const float*)d_in[7];
  float* out = (float*)d_out;

  // Workspace layout (128 MiB total, lifetime-aliased):
  //   [0,16)   qb   [B*S,E]  q-projection (bf16), lives to the final epilogue (residual)
  //   [16,32)  kb   [B*S,E]  k-projection; DEAD after scores GEMM -> reused as ob
  //   [32,48)  vT   [E,B*S]  v-projection transposed; dead after attn@V
  //   [48,50)  Wqb,Wkb,Wvb,Wpb (bf16 weights, 0.5 MiB each)
  //   [64,128) sc   [B,S,S]  scores/probs; BEFORE scores GEMM this region holds
  //            the bf16 casts of Q (at 64) and K (at 80) -- dead by then.
  char* ws = (char*)d_ws;
  const unsigned long long MB = 1024ull * 1024ull;
  __hip_bfloat16* qb = (__hip_bfloat16*)(ws + 0 * MB);
  __hip_bfloat16* kb = (__hip_bfloat16*)(ws + 16 * MB);
  __hip_bfloat16* ob = kb;  // alias, disjoint lifetime
  __hip_bfloat16* vT = (__hip_bfloat16*)(ws + 32 * MB);
  __hip_bfloat16* Wqb = (__hip_bfloat16*)(ws + 48 * MB);
  __hip_bfloat16* Wkb = Wqb + 512 * 512;
  __hip_bfloat16* Wvb = Wkb + 512 * 512;
  __hip_bfloat16* Wpb = Wvb + 512 * 512;
  __hip_bfloat16* sc = (__hip_bfloat16*)(ws + 64 * MB);
  __hip_bfloat16* Qc = sc;                 // alias, dead before scores GEMM
  __hip_bfloat16* Kc = sc + 8ull * MB;     // (8 MiB elements = 16 MiB bytes)

  dim3 blk(256, 1, 1);
  const int nQK = BB * SS * EE;  // 8.4M
  const int nW = EE * EE;        // 262k

  cast_f32_bf16<<<dim3(nQK / 2048, 1, 1), blk, 0, stream>>>(Q, Qc, nQK);
  cast_f32_bf16<<<dim3(nQK / 2048, 1, 1), blk, 0, stream>>>(K, Kc, nQK);
  cast_f32_bf16<<<dim3(nW / 2048, 1, 1), blk, 0, stream>>>(Wq, Wqb, nW);
  cast_f32_bf16<<<dim3(nW / 2048, 1, 1), blk, 0, stream>>>(Wk, Wkb, nW);
  cast_f32_bf16<<<dim3(nW / 2048, 1, 1), blk, 0, stream>>>(Wv, Wvb, nW);
  cast_f32_bf16<<<dim3(nW / 2048, 1, 1), blk, 0, stream>>>(Wp, Wpb, nW);

  EpiParams ep0{};

  // q = Q @ Wq^T ; k = K @ Wk^T   (bf16 out)
  gemm_bt<EPI_BF16><<<dim3(EE / 128, (BB * SS) / 128, 1), blk, 0, stream>>>(
      Qc, Wqb, qb, BB * SS, EE, EE, EE, EE, EE, 0ull, 0ull, 0ull, ep0);
  gemm_bt<EPI_BF16><<<dim3(EE / 128, (BB * SS) / 128, 1), blk, 0, stream>>>(
      Kc, Wkb, kb, BB * SS, EE, EE, EE, EE, EE, 0ull, 0ull, 0ull, ep0);

  // v = K @ Wv^T, stored transposed as vT[e, b*S + s]
  EpiParams epv{};
  epv.trans_ld = BB * SS;
  gemm_bt<EPI_BF16_T><<<dim3(EE / 128, (BB * SS) / 128, 1), blk, 0, stream>>>(
      Kc, Wvb, vT, BB * SS, EE, EE, EE, EE, EE, 0ull, 0ull, 0ull, epv);

  // scores[b] = (q_b @ k_b^T) * scale, masked -> bf16  (overwrites Qc/Kc region)
  EpiParams eps{};
  eps.scale = 0.044194173824159216f;  // 512^-0.5
  eps.mask = mask;
  eps.maskStrideZ = (unsigned long long)SS * SS;
  eps.mask_ld = SS;
  gemm_bt<EPI_MASK><<<dim3(SS / 128, SS / 128, BB), blk, 0, stream>>>(
      qb, kb, sc, SS, SS, EE, EE, EE, SS,
      (unsigned long long)SS * EE, (unsigned long long)SS * EE,
      (unsigned long long)SS * SS, eps);

  // softmax rows, in place
  softmax_rows<<<dim3(BB * SS, 1, 1), blk, 0, stream>>>(sc);

  // ob[b] = P_b @ v_b   (B^T-form: B = vT with ldb = B*S, batch offset = z*S)
  gemm_bt<EPI_BF16><<<dim3(EE / 128, SS / 128, BB), blk, 0, stream>>>(
      sc, vT, ob, SS, EE, SS, SS, BB * SS, EE,
      (unsigned long long)SS * SS, (unsigned long long)SS,
      (unsigned long long)SS * EE, ep0);

  // out = q + (ob @ Wp^T + bp)   (f32 out)
  EpiParams epf{};
  epf.bias = bp;
  epf.resid = qb;
  epf.resid_ld = EE;
  gemm_bt<EPI_FINAL><<<dim3(EE / 128, (BB * SS) / 128, 1), blk, 0, stream>>>(
      ob, Wpb, out, BB * SS, EE, EE, EE, EE, EE, 0ull, 0ull, 0ull, epf);
}

// Round 3
// 439.272 us; speedup vs baseline: 1.2498x; 1.0978x over previous
//
#include <hip/hip_runtime.h>
#include <hip/hip_bf16.h>

typedef short v8s __attribute__((ext_vector_type(8)));
typedef float v4f __attribute__((ext_vector_type(4)));

static constexpr int BB = 8;
static constexpr int SS = 2048;
static constexpr int EE = 512;

enum { EPI_BF16 = 0, EPI_SCALE = 1, EPI_FINAL = 2, EPI_KV = 3 };

struct EpiParams {
  float scale;
  const float* bias;
  const __hip_bfloat16* resid;
  int resid_ld;
  int trans_ld;
  __hip_bfloat16* c2;  // EPI_KV: transposed destination for cols >= nsplit
  int nsplit;
};

// Cast n (multiple of 8) f32 -> bf16, 8 elements/thread.
__global__ __launch_bounds__(256) void cast_f32_bf16(const float* __restrict__ x,
                                                     __hip_bfloat16* __restrict__ y, int n) {
  int i = (blockIdx.x * 256 + threadIdx.x) * 8;
  if (i >= n) return;
  float4 f0 = ((const float4*)(x + i))[0];
  float4 f1 = ((const float4*)(x + i))[1];
  alignas(16) __hip_bfloat16 h[8];
  h[0] = __float2bfloat16(f0.x); h[1] = __float2bfloat16(f0.y);
  h[2] = __float2bfloat16(f0.z); h[3] = __float2bfloat16(f0.w);
  h[4] = __float2bfloat16(f1.x); h[5] = __float2bfloat16(f1.y);
  h[6] = __float2bfloat16(f1.z); h[7] = __float2bfloat16(f1.w);
  *(uint4*)(y + i) = *(uint4*)h;
}

// Stage one 128x32 bf16 tile (8 KB) into LDS via global_load_lds width=16.
// Chunk c = row*4 + kc (16B each); wave covers chunks [(wave*2+t)*64, +64).
// LDS dest is wave-uniform base + lane*16 (m104/m108) -> layout is linear row-major.
__device__ __forceinline__ void stage_tile(const __hip_bfloat16* __restrict__ G,
                                           int row0, int ld, int k0,
                                           __hip_bfloat16* lds, int wave, int lane) {
#pragma unroll
  for (int t = 0; t < 2; ++t) {
    const int c = (wave * 2 + t) * 64 + lane;
    const int row = c >> 2;
    const int kc = c & 3;
    const __hip_bfloat16* g = G + (unsigned long long)(row0 + row) * ld + k0 + kc * 8;
    __builtin_amdgcn_global_load_lds(
        (const __attribute__((address_space(1))) void*)g,
        (__attribute__((address_space(3))) void*)(lds + (wave * 2 + t) * 512),
        16, 0, 0);
  }
}

// C = A @ B^T, A[M,K] (lda), B[N,K] (ldb), all bf16 in. 128x128 tile, BK=32,
// 256 threads = 4 waves in 2x2, each wave 64x64 via 4x4 of 16x16x32 bf16 MFMA.
template <int EPI>
__global__ __launch_bounds__(256, 2) void gemm_bt(
    const __hip_bfloat16* __restrict__ Ag, const __hip_bfloat16* __restrict__ Bg,
    void* __restrict__ Cg, int M, int N, int K, int lda, int ldb, int ldc,
    unsigned long long strideAz, unsigned long long strideBz, unsigned long long strideCz,
    EpiParams ep) {
  __shared__ __hip_bfloat16 As[128 * 32];
  __shared__ __hip_bfloat16 Bs[128 * 32];

  const int tid = threadIdx.x;
  const int lane = tid & 63;
  const int wave = tid >> 6;
  const int wr = wave >> 1;
  const int wc = wave & 1;
  const int z = blockIdx.z;
  const int m0 = blockIdx.y * 128;
  const int n0 = blockIdx.x * 128;

  Ag += (unsigned long long)z * strideAz;
  Bg += (unsigned long long)z * strideBz;

  v4f acc[4][4];
  const v4f vzero = {0.f, 0.f, 0.f, 0.f};
#pragma unroll
  for (int i = 0; i < 4; ++i)
#pragma unroll
    for (int j = 0; j < 4; ++j) acc[i][j] = vzero;

  const int fr = lane & 15;
  const int fk = (lane >> 4) * 8;

  for (int k0 = 0; k0 < K; k0 += 32) {
    __syncthreads();
    stage_tile(Ag, m0, lda, k0, As, wave, lane);
    stage_tile(Bg, n0, ldb, k0, Bs, wave, lane);
    __syncthreads();

    v8s a[4], b[4];
#pragma unroll
    for (int i = 0; i < 4; ++i) a[i] = *(const v8s*)&As[(wr * 64 + i * 16 + fr) * 32 + fk];
#pragma unroll
    for (int j = 0; j < 4; ++j) b[j] = *(const v8s*)&Bs[(wc * 64 + j * 16 + fr) * 32 + fk];
#pragma unroll
    for (int i = 0; i < 4; ++i)
#pragma unroll
      for (int j = 0; j < 4; ++j)
        acc[i][j] = __builtin_amdgcn_mfma_f32_16x16x32_bf16(a[i], b[j], acc[i][j], 0, 0, 0);
  }

  // Epilogue. C/D layout: col = lane&15, row = (lane>>4)*4 + reg (m89/m91)
  const int cf = lane & 15;
  const int rq = (lane >> 4) * 4;
  const int colBase = n0 + wc * 64;
  const int rowBase = m0 + wr * 64;

#pragma unroll
  for (int i = 0; i < 4; ++i) {
#pragma unroll
    for (int j = 0; j < 4; ++j) {
      const int col = colBase + j * 16 + cf;
      const int row0 = rowBase + i * 16 + rq;
      if constexpr (EPI == EPI_BF16) {
        __hip_bfloat16* C = (__hip_bfloat16*)Cg + (unsigned long long)z * strideCz;
#pragma unroll
        for (int r = 0; r < 4; ++r)
          C[(unsigned long long)(row0 + r) * ldc + col] = __float2bfloat16(acc[i][j][r]);
      } else if constexpr (EPI == EPI_SCALE) {
        __hip_bfloat16* C = (__hip_bfloat16*)Cg + (unsigned long long)z * strideCz;
#pragma unroll
        for (int r = 0; r < 4; ++r)
          C[(unsigned long long)(row0 + r) * ldc + col] = __float2bfloat16(acc[i][j][r] * ep.scale);
      } else if constexpr (EPI == EPI_KV) {
        // cols < nsplit: k-projection, row-major bf16. cols >= nsplit: v-projection,
        // stored transposed (4 consecutive rows -> one 8B packed store). Branch is
        // block-uniform (n0 multiple of 128, nsplit=512).
        if (colBase < ep.nsplit) {
          __hip_bfloat16* C = (__hip_bfloat16*)Cg;
#pragma unroll
          for (int r = 0; r < 4; ++r)
            C[(unsigned long long)(row0 + r) * ldc + col] = __float2bfloat16(acc[i][j][r]);
        } else {
          alignas(8) __hip_bfloat16 t4[4];
#pragma unroll
          for (int r = 0; r < 4; ++r) t4[r] = __float2bfloat16(acc[i][j][r]);
          *(ushort4*)&ep.c2[(unsigned long long)(col - ep.nsplit) * ep.trans_ld + row0] =
              *(ushort4*)t4;
        }
      } else {  // EPI_FINAL: out = acc + bias[col] + resid[row,col], f32 store
        float* C = (float*)Cg + (unsigned long long)z * strideCz;
        const float bi = ep.bias[col];
#pragma unroll
        for (int r = 0; r < 4; ++r) {
          float v = acc[i][j][r] + bi +
                    __bfloat162float(ep.resid[(unsigned long long)(row0 + r) * ep.resid_ld + col]);
          C[(unsigned long long)(row0 + r) * ldc + col] = v;
        }
      }
    }
  }
}

// In-place masked row softmax over bf16 scores: one block (256 thr) per row.
// Mask applied here (contiguous 8B/thread loads) instead of in the GEMM epilogue
// (which needed 64 scattered byte loads/thread).
__global__ __launch_bounds__(256) void softmax_rows(__hip_bfloat16* __restrict__ sc,
                                                    const unsigned char* __restrict__ mask) {
  const unsigned long long row = blockIdx.x;
  __hip_bfloat16* p = sc + row * (unsigned long long)SS;
  const int tid = threadIdx.x;
  const int lane = tid & 63;
  const int wv = tid >> 6;

  alignas(16) __hip_bfloat16 hv[8];
  ((uint4*)hv)[0] = *(const uint4*)&p[tid * 8];
  const unsigned long long mbits =
      *(const unsigned long long*)(mask + row * (unsigned long long)SS + tid * 8);

  float v[8];
  float m = -3.4e38f;
#pragma unroll
  for (int i = 0; i < 8; ++i) {
    v[i] = ((mbits >> (8 * i)) & 0xffull) ? -1e9f : __bfloat162float(hv[i]);
    m = fmaxf(m, v[i]);
  }
#pragma unroll
  for (int off = 32; off >= 1; off >>= 1) m = fmaxf(m, __shfl_xor(m, off));

  __shared__ float redm[4];
  __shared__ float reds[4];
  if (lane == 0) redm[wv] = m;
  __syncthreads();
  m = fmaxf(fmaxf(redm[0], redm[1]), fmaxf(redm[2], redm[3]));

  float s = 0.f;
#pragma unroll
  for (int i = 0; i < 8; ++i) {
    v[i] = __expf(v[i] - m);
    s += v[i];
  }
#pragma unroll
  for (int off = 32; off >= 1; off >>= 1) s += __shfl_xor(s, off);
  if (lane == 0) reds[wv] = s;
  __syncthreads();
  s = reds[0] + reds[1] + reds[2] + reds[3];
  const float inv = 1.0f / s;

#pragma unroll
  for (int i = 0; i < 8; ++i) hv[i] = __float2bfloat16(v[i] * inv);
  *(uint4*)&p[tid * 8] = ((uint4*)hv)[0];
}

extern "C" void kernel_launch(void* const* d_in, const int* in_sizes, int n_in,
                              void* d_out, int out_size, void* d_ws, size_t ws_size,
                              hipStream_t stream) {
  const float* Q = (const float*)d_in[0];
  const float* K = (const float*)d_in[1];
  const unsigned char* mask = (const unsigned char*)d_in[2];  // numpy bool, 1 byte
  const float* Wq = (const float*)d_in[3];
  const float* Wk = (const float*)d_in[4];
  const float* Wv = (const float*)d_in[5];
  const float* Wp = (const float*)d_in[6];
  const float* bp = (const float*)d_in[7];
  float* out = (float*)d_out;

  // Workspace layout (128 MiB, lifetime-aliased):
  //   [0,16)    qb  [B*S,E]   q-projection; lives to final epilogue (residual)
  //   [16,32)   kb  [B*S,E]   k-projection; dead after scores -> reused as ob
  //   [32,48)   vT  [E,B*S]   v-projection transposed; dead after attn@V
  //   [48,50)   Wqb (0.5M), Wkvb (1M contiguous: Wk rows then Wv rows), Wpb (0.5M)
  //   [64,128)  sc  [B,S,S]   scores/probs; before scores GEMM holds Qc (at 64)
  //             and Kc (at 80) bf16 casts -- dead by then.
  char* ws = (char*)d_ws;
  const unsigned long long MB = 1024ull * 1024ull;
  __hip_bfloat16* qb = (__hip_bfloat16*)(ws + 0 * MB);
  __hip_bfloat16* kb = (__hip_bfloat16*)(ws + 16 * MB);
  __hip_bfloat16* ob = kb;  // alias, disjoint lifetime
  __hip_bfloat16* vT = (__hip_bfloat16*)(ws + 32 * MB);
  __hip_bfloat16* Wqb = (__hip_bfloat16*)(ws + 48 * MB);
  __hip_bfloat16* Wkvb = Wqb + 512 * 512;            // [1024, 512]
  __hip_bfloat16* Wpb = Wkvb + 1024 * 512;
  __hip_bfloat16* sc = (__hip_bfloat16*)(ws + 64 * MB);
  __hip_bfloat16* Qc = sc;               // alias, dead before scores GEMM
  __hip_bfloat16* Kc = sc + 8ull * MB;

  dim3 blk(256, 1, 1);
  const int nQK = BB * SS * EE;
  const int nW = EE * EE;

  cast_f32_bf16<<<dim3(nQK / 2048, 1, 1), blk, 0, stream>>>(Q, Qc, nQK);
  cast_f32_bf16<<<dim3(nQK / 2048, 1, 1), blk, 0, stream>>>(K, Kc, nQK);
  cast_f32_bf16<<<dim3(nW / 2048, 1, 1), blk, 0, stream>>>(Wq, Wqb, nW);
  cast_f32_bf16<<<dim3(nW / 2048, 1, 1), blk, 0, stream>>>(Wk, Wkvb, nW);
  cast_f32_bf16<<<dim3(nW / 2048, 1, 1), blk, 0, stream>>>(Wv, Wkvb + 512 * 512, nW);
  cast_f32_bf16<<<dim3(nW / 2048, 1, 1), blk, 0, stream>>>(Wp, Wpb, nW);

  EpiParams ep0{};

  // q = Q @ Wq^T   (bf16 out)
  gemm_bt<EPI_BF16><<<dim3(EE / 128, (BB * SS) / 128, 1), blk, 0, stream>>>(
      Qc, Wqb, qb, BB * SS, EE, EE, EE, EE, EE, 0ull, 0ull, 0ull, ep0);

  // [k | v] = K @ [Wk; Wv]^T  fused N=1024; k -> kb row-major, v -> vT transposed
  EpiParams epkv{};
  epkv.nsplit = EE;
  epkv.trans_ld = BB * SS;
  epkv.c2 = vT;
  gemm_bt<EPI_KV><<<dim3(1024 / 128, (BB * SS) / 128, 1), blk, 0, stream>>>(
      Kc, Wkvb, kb, BB * SS, 1024, EE, EE, EE, EE, 0ull, 0ull, 0ull, epkv);

  // scores[b] = (q_b @ k_b^T) * scale -> bf16 (mask deferred to softmax)
  EpiParams eps{};
  eps.scale = 0.044194173824159216f;  // 512^-0.5
  gemm_bt<EPI_SCALE><<<dim3(SS / 128, SS / 128, BB), blk, 0, stream>>>(
      qb, kb, sc, SS, SS, EE, EE, EE, SS,
      (unsigned long long)SS * EE, (unsigned long long)SS * EE,
      (unsigned long long)SS * SS, eps);

  // masked softmax rows, in place
  softmax_rows<<<dim3(BB * SS, 1, 1), blk, 0, stream>>>(sc, mask);

  // ob[b] = P_b @ v_b   (B^T-form: B = vT with ldb = B*S, batch offset = z*S)
  gemm_bt<EPI_BF16><<<dim3(EE / 128, SS / 128, BB), blk, 0, stream>>>(
      sc, vT, ob, SS, EE, SS, SS, BB * SS, EE,
      (unsigned long long)SS * SS, (unsigned long long)SS,
      (unsigned long long)SS * EE, ep0);

  // out = q + (ob @ Wp^T + bp)   (f32 out)
  EpiParams epf{};
  epf.bias = bp;
  epf.resid = qb;
  epf.resid_ld = EE;
  gemm_bt<EPI_FINAL><<<dim3(EE / 128, (BB * SS) / 128, 1), blk, 0, stream>>>(
      ob, Wpb, out, BB * SS, EE, EE, EE, EE, EE, 0ull, 0ull, 0ull, epf);
}

// Round 4
// 408.346 us; speedup vs baseline: 1.3445x; 1.0757x over previous
//
#include <hip/hip_runtime.h>
#include <hip/hip_bf16.h>

typedef short v8s __attribute__((ext_vector_type(8)));
typedef float v4f __attribute__((ext_vector_type(4)));

static constexpr int BB = 8;
static constexpr int SS = 2048;
static constexpr int EE = 512;

enum { EPI_T = 0, EPI_SCALE_T = 1, EPI_FINAL_T = 2 };

struct EpiParams {
  float scale;
  const float* bias;               // EPI_FINAL_T: bias[row] (output col)
  const __hip_bfloat16* resid;     // EPI_FINAL_T: resid[col*resid_ld + row]
  int resid_ld;
  int trans_ld;                    // ld of the transposed C store
};

// Cast n (multiple of 8) f32 -> bf16, 8 elements/thread.
__global__ __launch_bounds__(256) void cast_f32_bf16(const float* __restrict__ x,
                                                     __hip_bfloat16* __restrict__ y, int n) {
  int i = (blockIdx.x * 256 + threadIdx.x) * 8;
  if (i >= n) return;
  float4 f0 = ((const float4*)(x + i))[0];
  float4 f1 = ((const float4*)(x + i))[1];
  alignas(16) __hip_bfloat16 h[8];
  h[0] = __float2bfloat16(f0.x); h[1] = __float2bfloat16(f0.y);
  h[2] = __float2bfloat16(f0.z); h[3] = __float2bfloat16(f0.w);
  h[4] = __float2bfloat16(f1.x); h[5] = __float2bfloat16(f1.y);
  h[6] = __float2bfloat16(f1.z); h[7] = __float2bfloat16(f1.w);
  *(uint4*)(y + i) = *(uint4*)h;
}

// Stage one 128x64 bf16 tile (16 KB) into LDS via global_load_lds width=16.
// LDS holds granules of 16B (8 bf16): position p = row*8 + g', containing the
// global granule g = g' ^ (row & 7)  (XOR swizzle -> conflict-free frag reads).
// LDS dest is wave-uniform base + lane*16 (m104/m108), so lane ℓ of sub-iter t
// fills p = (wave*4+t)*64 + ℓ; we pick the matching global source per lane.
__device__ __forceinline__ void stage_tile64(const __hip_bfloat16* __restrict__ G,
                                             int row0, int ld, int k0,
                                             __hip_bfloat16* lds, int wave, int lane) {
#pragma unroll
  for (int t = 0; t < 4; ++t) {
    const int p = (wave * 4 + t) * 64 + lane;
    const int row = p >> 3;
    const int gp = p & 7;
    const int g = gp ^ (row & 7);
    const __hip_bfloat16* src = G + (unsigned long long)(row0 + row) * ld + k0 + g * 8;
    __builtin_amdgcn_global_load_lds(
        (const __attribute__((address_space(1))) void*)src,
        (__attribute__((address_space(3))) void*)(lds + (wave * 4 + t) * 512),
        16, 0, 0);
  }
}

// C = A @ B^T, A[M,K] (lda), B[N,K] (ldb), bf16. 128x128 tile, BK=64,
// 256 threads = 4 waves in 2x2, each wave 64x64 via 4x4 of 16x16x32 bf16 MFMA.
// All epilogues store C TRANSPOSED: Cg[col*trans_ld + row], exploiting the
// 4-consecutive-rows-per-lane C-fragment (packed ushort4/float4 stores).
template <int EPI>
__global__ __launch_bounds__(256, 2) void gemm_bt(
    const __hip_bfloat16* __restrict__ Ag, const __hip_bfloat16* __restrict__ Bg,
    void* __restrict__ Cg, int M, int N, int K, int lda, int ldb,
    unsigned long long strideAz, unsigned long long strideBz, unsigned long long strideCz,
    EpiParams ep) {
  __shared__ __hip_bfloat16 As[128 * 64];
  __shared__ __hip_bfloat16 Bs[128 * 64];

  const int tid = threadIdx.x;
  const int lane = tid & 63;
  const int wave = tid >> 6;
  const int wr = wave >> 1;
  const int wc = wave & 1;
  const int z = blockIdx.z;
  const int m0 = blockIdx.y * 128;
  const int n0 = blockIdx.x * 128;

  Ag += (unsigned long long)z * strideAz;
  Bg += (unsigned long long)z * strideBz;

  v4f acc[4][4];
  const v4f vzero = {0.f, 0.f, 0.f, 0.f};
#pragma unroll
  for (int i = 0; i < 4; ++i)
#pragma unroll
    for (int j = 0; j < 4; ++j) acc[i][j] = vzero;

  const int fr = lane & 15;
  const int fq = lane >> 4;  // quad index -> k-granule within half-tile

  for (int k0 = 0; k0 < K; k0 += 64) {
    __syncthreads();
    stage_tile64(Ag, m0, lda, k0, As, wave, lane);
    stage_tile64(Bg, n0, ldb, k0, Bs, wave, lane);
    __syncthreads();

#pragma unroll
    for (int ks = 0; ks < 2; ++ks) {
      const int gq = ks * 4 + fq;  // global k-granule 0..7
      v8s a[4], b[4];
#pragma unroll
      for (int i = 0; i < 4; ++i) {
        const int r = wr * 64 + i * 16 + fr;
        a[i] = *(const v8s*)&As[r * 64 + ((gq ^ (r & 7)) * 8)];
      }
#pragma unroll
      for (int j = 0; j < 4; ++j) {
        const int r = wc * 64 + j * 16 + fr;
        b[j] = *(const v8s*)&Bs[r * 64 + ((gq ^ (r & 7)) * 8)];
      }
#pragma unroll
      for (int i = 0; i < 4; ++i)
#pragma unroll
        for (int j = 0; j < 4; ++j)
          acc[i][j] = __builtin_amdgcn_mfma_f32_16x16x32_bf16(a[i], b[j], acc[i][j], 0, 0, 0);
    }
  }

  // Epilogue. C/D layout: col = lane&15, row = (lane>>4)*4 + reg (m89/m91).
  const int cf = lane & 15;
  const int rq = (lane >> 4) * 4;
  const int colBase = n0 + wc * 64;
  const int rowBase = m0 + wr * 64;

#pragma unroll
  for (int i = 0; i < 4; ++i) {
    const int row0 = rowBase + i * 16 + rq;
    float4 b4;
    if constexpr (EPI == EPI_FINAL_T) b4 = *(const float4*)&ep.bias[row0];
#pragma unroll
    for (int j = 0; j < 4; ++j) {
      const int col = colBase + j * 16 + cf;
      if constexpr (EPI == EPI_T) {
        __hip_bfloat16* C = (__hip_bfloat16*)Cg + (unsigned long long)z * strideCz;
        alignas(8) __hip_bfloat16 t4[4];
#pragma unroll
        for (int r = 0; r < 4; ++r) t4[r] = __float2bfloat16(acc[i][j][r]);
        *(ushort4*)&C[(unsigned long long)col * ep.trans_ld + row0] = *(ushort4*)t4;
      } else if constexpr (EPI == EPI_SCALE_T) {
        __hip_bfloat16* C = (__hip_bfloat16*)Cg + (unsigned long long)z * strideCz;
        alignas(8) __hip_bfloat16 t4[4];
#pragma unroll
        for (int r = 0; r < 4; ++r) t4[r] = __float2bfloat16(acc[i][j][r] * ep.scale);
        *(ushort4*)&C[(unsigned long long)col * ep.trans_ld + row0] = *(ushort4*)t4;
      } else {  // EPI_FINAL_T: out[col][row0..3] = acc + bias[row] + resid[col][row]
        float* C = (float*)Cg + (unsigned long long)z * strideCz;
        ushort4 r4 = *(const ushort4*)&ep.resid[(unsigned long long)col * ep.resid_ld + row0];
        float4 o;
        o.x = acc[i][j][0] + b4.x + __bfloat162float(*(__hip_bfloat16*)&r4.x);
        o.y = acc[i][j][1] + b4.y + __bfloat162float(*(__hip_bfloat16*)&r4.y);
        o.z = acc[i][j][2] + b4.z + __bfloat162float(*(__hip_bfloat16*)&r4.z);
        o.w = acc[i][j][3] + b4.w + __bfloat162float(*(__hip_bfloat16*)&r4.w);
        *(float4*)&C[(unsigned long long)col * ep.trans_ld + row0] = o;
      }
    }
  }
}

// In-place masked row softmax over bf16 scores: one block (256 thr) per row.
__global__ __launch_bounds__(256) void softmax_rows(__hip_bfloat16* __restrict__ sc,
                                                    const unsigned char* __restrict__ mask) {
  const unsigned long long row = blockIdx.x;
  __hip_bfloat16* p = sc + row * (unsigned long long)SS;
  const int tid = threadIdx.x;
  const int lane = tid & 63;
  const int wv = tid >> 6;

  alignas(16) __hip_bfloat16 hv[8];
  ((uint4*)hv)[0] = *(const uint4*)&p[tid * 8];
  const unsigned long long mbits =
      *(const unsigned long long*)(mask + row * (unsigned long long)SS + tid * 8);

  float v[8];
  float m = -3.4e38f;
#pragma unroll
  for (int i = 0; i < 8; ++i) {
    v[i] = ((mbits >> (8 * i)) & 0xffull) ? -1e9f : __bfloat162float(hv[i]);
    m = fmaxf(m, v[i]);
  }
#pragma unroll
  for (int off = 32; off >= 1; off >>= 1) m = fmaxf(m, __shfl_xor(m, off));

  __shared__ float redm[4];
  __shared__ float reds[4];
  if (lane == 0) redm[wv] = m;
  __syncthreads();
  m = fmaxf(fmaxf(redm[0], redm[1]), fmaxf(redm[2], redm[3]));

  float s = 0.f;
#pragma unroll
  for (int i = 0; i < 8; ++i) {
    v[i] = __expf(v[i] - m);
    s += v[i];
  }
#pragma unroll
  for (int off = 32; off >= 1; off >>= 1) s += __shfl_xor(s, off);
  if (lane == 0) reds[wv] = s;
  __syncthreads();
  s = reds[0] + reds[1] + reds[2] + reds[3];
  const float inv = 1.0f / s;

#pragma unroll
  for (int i = 0; i < 8; ++i) hv[i] = __float2bfloat16(v[i] * inv);
  *(uint4*)&p[tid * 8] = ((uint4*)hv)[0];
}

extern "C" void kernel_launch(void* const* d_in, const int* in_sizes, int n_in,
                              void* d_out, int out_size, void* d_ws, size_t ws_size,
                              hipStream_t stream) {
  const float* Q = (const float*)d_in[0];
  const float* K = (const float*)d_in[1];
  const unsigned char* mask = (const unsigned char*)d_in[2];  // numpy bool, 1 byte
  const float* Wq = (const float*)d_in[3];
  const float* Wk = (const float*)d_in[4];
  const float* Wv = (const float*)d_in[5];
  const float* Wp = (const float*)d_in[6];
  const float* bp = (const float*)d_in[7];
  float* out = (float*)d_out;

  // Workspace layout (128 MiB, lifetime-aliased):
  //   [0,16)    qb  [B*S,E]   q-projection; lives to final epilogue (residual)
  //   [16,32)   kb  [B*S,E]   k-projection; dead after scores -> reused as ob
  //   [32,48)   vT  [E,B*S]   v-projection transposed; dead after attn@V
  //   [48,50)   Wqb, Wkb, Wvb, Wpb (bf16 weights, 0.5 MiB each)
  //   [64,128)  sc  [B,S,S]   scores/probs; before scores GEMM holds Qc (at 64)
  //             and Kc (at 80) bf16 casts -- dead by then.
  char* ws = (char*)d_ws;
  const unsigned long long MB = 1024ull * 1024ull;
  __hip_bfloat16* qb = (__hip_bfloat16*)(ws + 0 * MB);
  __hip_bfloat16* kb = (__hip_bfloat16*)(ws + 16 * MB);
  __hip_bfloat16* ob = kb;  // alias, disjoint lifetime
  __hip_bfloat16* vT = (__hip_bfloat16*)(ws + 32 * MB);
  __hip_bfloat16* Wqb = (__hip_bfloat16*)(ws + 48 * MB);
  __hip_bfloat16* Wkb = Wqb + 512 * 512;
  __hip_bfloat16* Wvb = Wkb + 512 * 512;
  __hip_bfloat16* Wpb = Wvb + 512 * 512;
  __hip_bfloat16* sc = (__hip_bfloat16*)(ws + 64 * MB);
  __hip_bfloat16* Qc = sc;               // alias, dead before scores GEMM
  __hip_bfloat16* Kc = sc + 8ull * MB;

  dim3 blk(256, 1, 1);
  const int nQK = BB * SS * EE;
  const int nW = EE * EE;

  cast_f32_bf16<<<dim3(nQK / 2048, 1, 1), blk, 0, stream>>>(Q, Qc, nQK);
  cast_f32_bf16<<<dim3(nQK / 2048, 1, 1), blk, 0, stream>>>(K, Kc, nQK);
  cast_f32_bf16<<<dim3(nW / 2048, 1, 1), blk, 0, stream>>>(Wq, Wqb, nW);
  cast_f32_bf16<<<dim3(nW / 2048, 1, 1), blk, 0, stream>>>(Wk, Wkb, nW);
  cast_f32_bf16<<<dim3(nW / 2048, 1, 1), blk, 0, stream>>>(Wv, Wvb, nW);
  cast_f32_bf16<<<dim3(nW / 2048, 1, 1), blk, 0, stream>>>(Wp, Wpb, nW);

  // q = (Wq @ Q^T)^T: C[f][s], stored transposed -> qb[s*E + f]  (packed 8B)
  EpiParams epq{};
  epq.trans_ld = EE;
  gemm_bt<EPI_T><<<dim3((BB * SS) / 128, EE / 128, 1), blk, 0, stream>>>(
      Wqb, Qc, qb, EE, BB * SS, EE, EE, EE, 0ull, 0ull, 0ull, epq);

  // k = (Wk @ K^T)^T -> kb[s*E + f]  (packed 8B)
  gemm_bt<EPI_T><<<dim3((BB * SS) / 128, EE / 128, 1), blk, 0, stream>>>(
      Wkb, Kc, kb, EE, BB * SS, EE, EE, EE, 0ull, 0ull, 0ull, epq);

  // v^T = (K @ Wv^T)^T: C[s][e] stored transposed -> vT[e*(B*S) + s]  (packed 8B)
  EpiParams epv{};
  epv.trans_ld = BB * SS;
  gemm_bt<EPI_T><<<dim3(EE / 128, (BB * SS) / 128, 1), blk, 0, stream>>>(
      Kc, Wvb, vT, BB * SS, EE, EE, EE, EE, 0ull, 0ull, 0ull, epv);

  // scores^T trick: C = k @ q^T -> C[kk][q]; transposed store -> sc[q*S + kk] (packed)
  EpiParams eps{};
  eps.scale = 0.044194173824159216f;  // 512^-0.5
  eps.trans_ld = SS;
  gemm_bt<EPI_SCALE_T><<<dim3(SS / 128, SS / 128, BB), blk, 0, stream>>>(
      kb, qb, sc, SS, SS, EE, EE, EE,
      (unsigned long long)SS * EE, (unsigned long long)SS * EE,
      (unsigned long long)SS * SS, eps);

  // masked softmax rows, in place
  softmax_rows<<<dim3(BB * SS, 1, 1), blk, 0, stream>>>(sc, mask);

  // ob = (vT @ P^T)^T: A = vT[e, k] (lda=B*S), B = P rows (ldb=S); C[e][q]
  // stored transposed -> ob[q*E + e]  (packed 8B)
  EpiParams epo{};
  epo.trans_ld = EE;
  gemm_bt<EPI_T><<<dim3(SS / 128, EE / 128, BB), blk, 0, stream>>>(
      vT, sc, ob, EE, SS, SS, BB * SS, SS,
      (unsigned long long)SS, (unsigned long long)SS * SS,
      (unsigned long long)SS * EE, epo);

  // out = q + (Wp @ ob^T)^T + bp: C[f][s] transposed-stored as float4 with fused
  // bias[f] + residual qb[s][f] (packed 8B read)
  EpiParams epf{};
  epf.bias = bp;
  epf.resid = qb;
  epf.resid_ld = EE;
  epf.trans_ld = EE;
  gemm_bt<EPI_FINAL_T><<<dim3((BB * SS) / 128, EE / 128, 1), blk, 0, stream>>>(
      Wpb, ob, out, EE, BB * SS, EE, EE, EE, 0ull, 0ull, 0ull, epf);
}

// Round 5
// 383.559 us; speedup vs baseline: 1.4314x; 1.0646x over previous
//
#include <hip/hip_runtime.h>
#include <hip/hip_bf16.h>

typedef short v8s __attribute__((ext_vector_type(8)));
typedef float v4f __attribute__((ext_vector_type(4)));

static constexpr int BB = 8, SS = 2048, EE = 512;

enum { EPI_BF16 = 0, EPI_SCALE = 1, EPI_FINAL = 2 };

struct EpiParams {
  float scale;
  const float* bias;            // EPI_FINAL: bias[col]
  const __hip_bfloat16* resid;  // EPI_FINAL: resid[row*resid_ld + col]
  int resid_ld;
};

// LDS union: staging (As 16K | Bs 16K) vs epilogue C-tile
//   bf16 tile 128 x 136  -> 34816 B (stride 272 B = 17*16: aligned, 2-way banks = free)
//   f32 half  64 x 132   -> 33792 B (stride 528 B = 33*16)
static constexpr int SMEM_BYTES = 34816;

// ---------------- merged f32->bf16 cast (6 tensors, one launch) ----------------
struct CastParams {
  const float* src[6];
  __hip_bfloat16* dst[6];
  int nblk[6];  // blocks per segment; each block converts 2048 elements
};

__global__ __launch_bounds__(256) void cast_multi(CastParams cp) {
  int b = blockIdx.x, seg = 0, base = 0;
  while (b - base >= cp.nblk[seg]) { base += cp.nblk[seg]; ++seg; }
  const float* x = cp.src[seg] + (unsigned long long)(b - base) * 2048;
  __hip_bfloat16* y = cp.dst[seg] + (unsigned long long)(b - base) * 2048;
  int i = threadIdx.x * 8;
  float4 f0 = ((const float4*)(x + i))[0];
  float4 f1 = ((const float4*)(x + i))[1];
  alignas(16) __hip_bfloat16 h[8];
  h[0] = __float2bfloat16(f0.x); h[1] = __float2bfloat16(f0.y);
  h[2] = __float2bfloat16(f0.z); h[3] = __float2bfloat16(f0.w);
  h[4] = __float2bfloat16(f1.x); h[5] = __float2bfloat16(f1.y);
  h[6] = __float2bfloat16(f1.z); h[7] = __float2bfloat16(f1.w);
  *(uint4*)(y + i) = *(uint4*)h;
}

// ---------------- GEMM core ----------------
// Stage one 128x64 bf16 tile (16 KB) into LDS via global_load_lds width=16.
// XOR swizzle: LDS granule g' at row holds global granule g = g' ^ (row&7).
__device__ __forceinline__ void stage_tile64(const __hip_bfloat16* __restrict__ G,
                                             int row0, int ld, int k0,
                                             __hip_bfloat16* lds, int wave, int lane) {
#pragma unroll
  for (int t = 0; t < 4; ++t) {
    const int p = (wave * 4 + t) * 64 + lane;
    const int row = p >> 3;
    const int g = (p & 7) ^ (row & 7);
    const __hip_bfloat16* src = G + (unsigned long long)(row0 + row) * ld + k0 + g * 8;
    __builtin_amdgcn_global_load_lds(
        (const __attribute__((address_space(1))) void*)src,
        (__attribute__((address_space(3))) void*)(lds + (wave * 4 + t) * 512),
        16, 0, 0);
  }
}

// C = A @ B^T, bf16 in. 128x128 tile, BK=64, 256 threads = 4 waves (2x2),
// each wave 64x64 via 4x4 of 16x16x32 bf16 MFMA. Epilogue routes C through
// LDS (union with staging buffers) for fully coalesced 16 B/lane stores.
template <int EPI>
__device__ __forceinline__ void gemm_body(const __hip_bfloat16* Ag, const __hip_bfloat16* Bg,
                                          void* Cg, int K, int lda, int ldb, int ldc,
                                          int m0, int n0, const EpiParams& ep,
                                          unsigned char* smem) {
  __hip_bfloat16* As = (__hip_bfloat16*)smem;
  __hip_bfloat16* Bs = As + 128 * 64;

  const int tid = threadIdx.x;
  const int lane = tid & 63;
  const int wave = tid >> 6;
  const int wr = wave >> 1;
  const int wc = wave & 1;

  v4f acc[4][4];
  const v4f vzero = {0.f, 0.f, 0.f, 0.f};
#pragma unroll
  for (int i = 0; i < 4; ++i)
#pragma unroll
    for (int j = 0; j < 4; ++j) acc[i][j] = vzero;

  const int fr = lane & 15;
  const int fq = lane >> 4;

  for (int k0 = 0; k0 < K; k0 += 64) {
    __syncthreads();
    stage_tile64(Ag, m0, lda, k0, As, wave, lane);
    stage_tile64(Bg, n0, ldb, k0, Bs, wave, lane);
    __syncthreads();

#pragma unroll
    for (int ks = 0; ks < 2; ++ks) {
      const int gq = ks * 4 + fq;
      v8s a[4], b[4];
#pragma unroll
      for (int i = 0; i < 4; ++i) {
        const int r = wr * 64 + i * 16 + fr;
        a[i] = *(const v8s*)&As[r * 64 + ((gq ^ (r & 7)) * 8)];
      }
#pragma unroll
      for (int j = 0; j < 4; ++j) {
        const int r = wc * 64 + j * 16 + fr;
        b[j] = *(const v8s*)&Bs[r * 64 + ((gq ^ (r & 7)) * 8)];
      }
#pragma unroll
      for (int i = 0; i < 4; ++i)
#pragma unroll
        for (int j = 0; j < 4; ++j)
          acc[i][j] = __builtin_amdgcn_mfma_f32_16x16x32_bf16(a[i], b[j], acc[i][j], 0, 0, 0);
    }
  }

  // C/D frag layout: col = lane&15, row = (lane>>4)*4 + reg (m89/m91)
  const int cf = lane & 15;
  const int rq = (lane >> 4) * 4;

  __syncthreads();  // staging region dead; reuse as C-tile

  if constexpr (EPI != EPI_FINAL) {
    __hip_bfloat16* Ct = (__hip_bfloat16*)smem;
    const int ST = 136;
#pragma unroll
    for (int i = 0; i < 4; ++i) {
      const int rl = wr * 64 + i * 16 + rq;
#pragma unroll
      for (int j = 0; j < 4; ++j) {
        const int col = wc * 64 + j * 16 + cf;
#pragma unroll
        for (int r = 0; r < 4; ++r) {
          float v = acc[i][j][r];
          if constexpr (EPI == EPI_SCALE) v *= ep.scale;
          Ct[(rl + r) * ST + col] = __float2bfloat16(v);
        }
      }
    }
    __syncthreads();
    __hip_bfloat16* C = (__hip_bfloat16*)Cg;
#pragma unroll
    for (int c = 0; c < 8; ++c) {
      const int idx = c * 256 + tid;   // 2048 chunks of 8 bf16
      const int row = idx >> 4;
      const int colc = (idx & 15) * 8;
      *(v8s*)&C[(unsigned long long)(m0 + row) * ldc + n0 + colc] =
          *(const v8s*)&Ct[row * ST + colc];
    }
  } else {
    float* Cf = (float*)smem;
    const int ST = 132;
    float* C = (float*)Cg;
#pragma unroll
    for (int h = 0; h < 2; ++h) {
      if (wr == h) {
#pragma unroll
        for (int i = 0; i < 4; ++i) {
          const int rl = i * 16 + rq;
#pragma unroll
          for (int j = 0; j < 4; ++j) {
            const int col = wc * 64 + j * 16 + cf;
#pragma unroll
            for (int r = 0; r < 4; ++r) Cf[(rl + r) * ST + col] = acc[i][j][r];
          }
        }
      }
      __syncthreads();
#pragma unroll
      for (int c = 0; c < 8; ++c) {
        const int idx = c * 256 + tid;  // 2048 float4 chunks over 64x128
        const int row = idx >> 5;
        const int colc = (idx & 31) * 4;
        const int grow = m0 + h * 64 + row;
        const int gcol = n0 + colc;
        float4 v = *(const float4*)&Cf[row * ST + colc];
        float4 b4 = *(const float4*)&ep.bias[gcol];
        ushort4 r4 = *(const ushort4*)&ep.resid[(unsigned long long)grow * ep.resid_ld + gcol];
        v.x += b4.x + __bfloat162float(*(__hip_bfloat16*)&r4.x);
        v.y += b4.y + __bfloat162float(*(__hip_bfloat16*)&r4.y);
        v.z += b4.z + __bfloat162float(*(__hip_bfloat16*)&r4.z);
        v.w += b4.w + __bfloat162float(*(__hip_bfloat16*)&r4.w);
        *(float4*)&C[(unsigned long long)grow * ldc + gcol] = v;
      }
      if (h == 0) __syncthreads();
    }
  }
}

template <int EPI>
__global__ __launch_bounds__(256, 3) void gemm_bt(
    const __hip_bfloat16* __restrict__ Ag, const __hip_bfloat16* __restrict__ Bg,
    void* __restrict__ Cg, int K, int lda, int ldb, int ldc,
    unsigned long long sAz, unsigned long long sBz, unsigned long long sCz, EpiParams ep) {
  __shared__ __align__(16) unsigned char smem[SMEM_BYTES];
  const unsigned long long z = blockIdx.z;
  void* Cz;
  if constexpr (EPI == EPI_FINAL) Cz = (void*)((float*)Cg + z * sCz);
  else Cz = (void*)((__hip_bfloat16*)Cg + z * sCz);
  gemm_body<EPI>(Ag + z * sAz, Bg + z * sBz, Cz, K, lda, ldb, ldc,
                 blockIdx.y * 128, blockIdx.x * 128, ep, smem);
}

// q/k/v projections in one launch. grid = (128, 4, 3).
// z=0: q = Qc@Wq^T -> qb[s][f]   (bm=bx over s, bn=by over f)
// z=1: k = Kc@Wk^T -> kb[s][f]
// z=2: v^T = Wv@Kc^T -> vT[e][s] (bm=by over e, bn=bx over s)
struct QKVParams {
  const __hip_bfloat16* A[3];
  const __hip_bfloat16* B[3];
  __hip_bfloat16* C[3];
  int ldc[3];
};

__global__ __launch_bounds__(256, 3) void gemm_qkv(QKVParams p) {
  __shared__ __align__(16) unsigned char smem[SMEM_BYTES];
  const int z = blockIdx.z;
  const int bm = (z == 2) ? blockIdx.y : blockIdx.x;
  const int bn = (z == 2) ? blockIdx.x : blockIdx.y;
  EpiParams ep{};
  gemm_body<EPI_BF16>(p.A[z], p.B[z], p.C[z], EE, EE, EE, p.ldc[z],
                      bm * 128, bn * 128, ep, smem);
}

// ---------------- masked softmax ----------------
__global__ __launch_bounds__(256) void softmax_rows(__hip_bfloat16* __restrict__ sc,
                                                    const unsigned char* __restrict__ mask) {
  const unsigned long long row = blockIdx.x;
  __hip_bfloat16* p = sc + row * (unsigned long long)SS;
  const int tid = threadIdx.x;
  const int lane = tid & 63;
  const int wv = tid >> 6;

  alignas(16) __hip_bfloat16 hv[8];
  ((uint4*)hv)[0] = *(const uint4*)&p[tid * 8];
  const unsigned long long mbits =
      *(const unsigned long long*)(mask + row * (unsigned long long)SS + tid * 8);

  float v[8];
  float m = -3.4e38f;
#pragma unroll
  for (int i = 0; i < 8; ++i) {
    v[i] = ((mbits >> (8 * i)) & 0xffull) ? -1e9f : __bfloat162float(hv[i]);
    m = fmaxf(m, v[i]);
  }
#pragma unroll
  for (int off = 32; off >= 1; off >>= 1) m = fmaxf(m, __shfl_xor(m, off));

  __shared__ float redm[4];
  __shared__ float reds[4];
  if (lane == 0) redm[wv] = m;
  __syncthreads();
  m = fmaxf(fmaxf(redm[0], redm[1]), fmaxf(redm[2], redm[3]));

  float s = 0.f;
#pragma unroll
  for (int i = 0; i < 8; ++i) {
    v[i] = __expf(v[i] - m);
    s += v[i];
  }
#pragma unroll
  for (int off = 32; off >= 1; off >>= 1) s += __shfl_xor(s, off);
  if (lane == 0) reds[wv] = s;
  __syncthreads();
  s = reds[0] + reds[1] + reds[2] + reds[3];
  const float inv = 1.0f / s;

#pragma unroll
  for (int i = 0; i < 8; ++i) hv[i] = __float2bfloat16(v[i] * inv);
  *(uint4*)&p[tid * 8] = ((uint4*)hv)[0];
}

extern "C" void kernel_launch(void* const* d_in, const int* in_sizes, int n_in,
                              void* d_out, int out_size, void* d_ws, size_t ws_size,
                              hipStream_t stream) {
  const float* Q = (const float*)d_in[0];
  const float* K = (const float*)d_in[1];
  const unsigned char* mask = (const unsigned char*)d_in[2];  // numpy bool, 1 byte
  const float* Wq = (const float*)d_in[3];
  const float* Wk = (const float*)d_in[4];
  const float* Wv = (const float*)d_in[5];
  const float* Wp = (const float*)d_in[6];
  const float* bp = (const float*)d_in[7];
  float* out = (float*)d_out;

  // Workspace (128 MiB, lifetime-aliased):
  //   [0,16)   qb [B*S,E]; lives to final epilogue (residual)
  //   [16,32)  kb [B*S,E]; dead after scores -> reused as ob [B*S,E]
  //   [32,48)  vT [E,B*S]
  //   [48,50)  Wqb,Wkb,Wvb,Wpb
  //   [64,128) sc [B,S,S]; before scores holds Qc (64) / Kc (80) casts
  char* ws = (char*)d_ws;
  const unsigned long long MB = 1024ull * 1024ull;
  __hip_bfloat16* qb = (__hip_bfloat16*)(ws + 0 * MB);
  __hip_bfloat16* kb = (__hip_bfloat16*)(ws + 16 * MB);
  __hip_bfloat16* ob = kb;  // alias, disjoint lifetime
  __hip_bfloat16* vT = (__hip_bfloat16*)(ws + 32 * MB);
  __hip_bfloat16* Wqb = (__hip_bfloat16*)(ws + 48 * MB);
  __hip_bfloat16* Wkb = Wqb + 512 * 512;
  __hip_bfloat16* Wvb = Wkb + 512 * 512;
  __hip_bfloat16* Wpb = Wvb + 512 * 512;
  __hip_bfloat16* sc = (__hip_bfloat16*)(ws + 64 * MB);
  __hip_bfloat16* Qc = sc;
  __hip_bfloat16* Kc = sc + 8ull * MB;

  dim3 blk(256, 1, 1);
  const int nQK = BB * SS * EE;  // 8.4M
  const int nW = EE * EE;

  // 1) all casts in one launch
  CastParams cp;
  cp.src[0] = Q;  cp.dst[0] = Qc;  cp.nblk[0] = nQK / 2048;
  cp.src[1] = K;  cp.dst[1] = Kc;  cp.nblk[1] = nQK / 2048;
  cp.src[2] = Wq; cp.dst[2] = Wqb; cp.nblk[2] = nW / 2048;
  cp.src[3] = Wk; cp.dst[3] = Wkb; cp.nblk[3] = nW / 2048;
  cp.src[4] = Wv; cp.dst[4] = Wvb; cp.nblk[4] = nW / 2048;
  cp.src[5] = Wp; cp.dst[5] = Wpb; cp.nblk[5] = nW / 2048;
  int totalBlk = 2 * (nQK / 2048) + 4 * (nW / 2048);
  cast_multi<<<dim3(totalBlk, 1, 1), blk, 0, stream>>>(cp);

  // 2) q/k/v projections, one launch
  QKVParams qp;
  qp.A[0] = Qc;  qp.B[0] = Wqb; qp.C[0] = qb; qp.ldc[0] = EE;
  qp.A[1] = Kc;  qp.B[1] = Wkb; qp.C[1] = kb; qp.ldc[1] = EE;
  qp.A[2] = Wvb; qp.B[2] = Kc;  qp.C[2] = vT; qp.ldc[2] = BB * SS;
  gemm_qkv<<<dim3((BB * SS) / 128, EE / 128, 3), blk, 0, stream>>>(qp);

  // 3) scores[b] = (q_b @ k_b^T) * scale -> sc[q][k] bf16 (mask in softmax)
  EpiParams eps{};
  eps.scale = 0.044194173824159216f;  // 512^-0.5
  gemm_bt<EPI_SCALE><<<dim3(SS / 128, SS / 128, BB), blk, 0, stream>>>(
      qb, kb, sc, EE, EE, EE, SS,
      (unsigned long long)SS * EE, (unsigned long long)SS * EE,
      (unsigned long long)SS * SS, eps);

  // 4) masked softmax rows, in place
  softmax_rows<<<dim3(BB * SS, 1, 1), blk, 0, stream>>>(sc, mask);

  // 5) ob[b] = P_b @ v_b : A=sc (lda=S), B=vT rows=e (ldb=B*S, batch offset S)
  EpiParams ep0{};
  gemm_bt<EPI_BF16><<<dim3(EE / 128, SS / 128, BB), blk, 0, stream>>>(
      sc, vT, ob, SS, SS, BB * SS, EE,
      (unsigned long long)SS * SS, (unsigned long long)SS,
      (unsigned long long)SS * EE, ep0);

  // 6) out = q + (ob @ Wp^T + bp)  f32
  EpiParams epf{};
  epf.bias = bp;
  epf.resid = qb;
  epf.resid_ld = EE;
  gemm_bt<EPI_FINAL><<<dim3(EE / 128, (BB * SS) / 128, 1), blk, 0, stream>>>(
      ob, Wpb, out, EE, EE, EE, EE, 0ull, 0ull, 0ull, epf);
}

// Round 6
// 374.379 us; speedup vs baseline: 1.4665x; 1.0245x over previous
//
#include <hip/hip_runtime.h>
#include <hip/hip_bf16.h>

typedef short v8s __attribute__((ext_vector_type(8)));
typedef float v4f __attribute__((ext_vector_type(4)));

static constexpr int BB = 8, SS = 2048, EE = 512;

enum { EPI_BF16 = 0, EPI_SCALE = 1, EPI_FINAL = 2 };

struct EpiParams {
  float scale;
  const float* bias;            // EPI_FINAL: bias[col]
  const __hip_bfloat16* resid;  // EPI_FINAL: resid[row*resid_ld + col]
  int resid_ld;
};

// LDS union: staging (As 16K | Bs 16K) vs epilogue C-tile
//   bf16 tile 128 x 136  -> 34816 B (stride 272 B: 16B-aligned, 2-way banks = free)
//   f32 half  64 x 132   -> 33792 B
static constexpr int SMEM_BYTES = 34816;

// ---------------- weights f32->bf16 cast (4 tensors, one tiny launch) ----------------
struct CastParams {
  const float* src[4];
  __hip_bfloat16* dst[4];
};

__global__ __launch_bounds__(256) void cast_weights(CastParams cp) {
  const int seg = blockIdx.x >> 7;           // 128 blocks per 512x512 tensor
  const int b = blockIdx.x & 127;
  const float* x = cp.src[seg] + (unsigned long long)b * 2048;
  __hip_bfloat16* y = cp.dst[seg] + (unsigned long long)b * 2048;
  int i = threadIdx.x * 8;
  float4 f0 = ((const float4*)(x + i))[0];
  float4 f1 = ((const float4*)(x + i))[1];
  alignas(16) __hip_bfloat16 h[8];
  h[0] = __float2bfloat16(f0.x); h[1] = __float2bfloat16(f0.y);
  h[2] = __float2bfloat16(f0.z); h[3] = __float2bfloat16(f0.w);
  h[4] = __float2bfloat16(f1.x); h[5] = __float2bfloat16(f1.y);
  h[6] = __float2bfloat16(f1.z); h[7] = __float2bfloat16(f1.w);
  *(uint4*)(y + i) = *(uint4*)h;
}

// ---------------- GEMM staging ----------------
// bf16 source: one 128x64 tile (16 KB) via global_load_lds width=16.
// XOR swizzle: LDS granule g' at row holds global granule g = g' ^ (row&7).
__device__ __forceinline__ void stage_tile64(const __hip_bfloat16* __restrict__ G,
                                             int row0, int ld, int k0,
                                             __hip_bfloat16* lds, int wave, int lane) {
#pragma unroll
  for (int t = 0; t < 4; ++t) {
    const int p = (wave * 4 + t) * 64 + lane;
    const int row = p >> 3;
    const int g = (p & 7) ^ (row & 7);
    const __hip_bfloat16* src = G + (unsigned long long)(row0 + row) * ld + k0 + g * 8;
    __builtin_amdgcn_global_load_lds(
        (const __attribute__((address_space(1))) void*)src,
        (__attribute__((address_space(3))) void*)(lds + (wave * 4 + t) * 512),
        16, 0, 0);
  }
}

// f32 source: load 8 floats/lane, convert, ds_write_b128 into the same swizzled
// layout (fused cast -- the VALU work overlaps with MFMA, m114). Per 8-lane
// group the global read is 256 B contiguous (swizzle permutes within the row).
__device__ __forceinline__ void stage_tile64_f32(const float* __restrict__ G,
                                                 int row0, int ld, int k0,
                                                 __hip_bfloat16* lds, int tid) {
#pragma unroll
  for (int c = 0; c < 4; ++c) {
    const int p = c * 256 + tid;
    const int row = p >> 3;
    const int g = (p & 7) ^ (row & 7);
    const float* src = G + (unsigned long long)(row0 + row) * ld + k0 + g * 8;
    float4 f0 = ((const float4*)src)[0];
    float4 f1 = ((const float4*)src)[1];
    alignas(16) __hip_bfloat16 h[8];
    h[0] = __float2bfloat16(f0.x); h[1] = __float2bfloat16(f0.y);
    h[2] = __float2bfloat16(f0.z); h[3] = __float2bfloat16(f0.w);
    h[4] = __float2bfloat16(f1.x); h[5] = __float2bfloat16(f1.y);
    h[6] = __float2bfloat16(f1.z); h[7] = __float2bfloat16(f1.w);
    *(uint4*)&lds[p * 8] = *(uint4*)h;
  }
}

// C = A @ B^T. 128x128 tile, BK=64, 256 threads = 4 waves (2x2), each wave
// 64x64 via 4x4 of 16x16x32 bf16 MFMA. A/B may be f32 (converted in staging).
// Epilogue routes C through LDS (union with staging) for coalesced stores.
template <int EPI, bool AF32, bool BF32>
__device__ __forceinline__ void gemm_body(const void* Agv, const void* Bgv,
                                          void* Cg, int K, int lda, int ldb, int ldc,
                                          int m0, int n0, const EpiParams& ep,
                                          unsigned char* smem) {
  __hip_bfloat16* As = (__hip_bfloat16*)smem;
  __hip_bfloat16* Bs = As + 128 * 64;

  const int tid = threadIdx.x;
  const int lane = tid & 63;
  const int wave = tid >> 6;
  const int wr = wave >> 1;
  const int wc = wave & 1;

  v4f acc[4][4];
  const v4f vzero = {0.f, 0.f, 0.f, 0.f};
#pragma unroll
  for (int i = 0; i < 4; ++i)
#pragma unroll
    for (int j = 0; j < 4; ++j) acc[i][j] = vzero;

  const int fr = lane & 15;
  const int fq = lane >> 4;

  for (int k0 = 0; k0 < K; k0 += 64) {
    __syncthreads();
    if constexpr (AF32)
      stage_tile64_f32((const float*)Agv, m0, lda, k0, As, tid);
    else
      stage_tile64((const __hip_bfloat16*)Agv, m0, lda, k0, As, wave, lane);
    if constexpr (BF32)
      stage_tile64_f32((const float*)Bgv, n0, ldb, k0, Bs, tid);
    else
      stage_tile64((const __hip_bfloat16*)Bgv, n0, ldb, k0, Bs, wave, lane);
    __syncthreads();

#pragma unroll
    for (int ks = 0; ks < 2; ++ks) {
      const int gq = ks * 4 + fq;
      v8s a[4], b[4];
#pragma unroll
      for (int i = 0; i < 4; ++i) {
        const int r = wr * 64 + i * 16 + fr;
        a[i] = *(const v8s*)&As[r * 64 + ((gq ^ (r & 7)) * 8)];
      }
#pragma unroll
      for (int j = 0; j < 4; ++j) {
        const int r = wc * 64 + j * 16 + fr;
        b[j] = *(const v8s*)&Bs[r * 64 + ((gq ^ (r & 7)) * 8)];
      }
#pragma unroll
      for (int i = 0; i < 4; ++i)
#pragma unroll
        for (int j = 0; j < 4; ++j)
          acc[i][j] = __builtin_amdgcn_mfma_f32_16x16x32_bf16(a[i], b[j], acc[i][j], 0, 0, 0);
    }
  }

  // C/D frag layout: col = lane&15, row = (lane>>4)*4 + reg (m89/m91)
  const int cf = lane & 15;
  const int rq = (lane >> 4) * 4;

  __syncthreads();  // staging region dead; reuse as C-tile

  if constexpr (EPI != EPI_FINAL) {
    __hip_bfloat16* Ct = (__hip_bfloat16*)smem;
    const int ST = 136;
#pragma unroll
    for (int i = 0; i < 4; ++i) {
      const int rl = wr * 64 + i * 16 + rq;
#pragma unroll
      for (int j = 0; j < 4; ++j) {
        const int col = wc * 64 + j * 16 + cf;
#pragma unroll
        for (int r = 0; r < 4; ++r) {
          float v = acc[i][j][r];
          if constexpr (EPI == EPI_SCALE) v *= ep.scale;
          Ct[(rl + r) * ST + col] = __float2bfloat16(v);
        }
      }
    }
    __syncthreads();
    __hip_bfloat16* C = (__hip_bfloat16*)Cg;
#pragma unroll
    for (int c = 0; c < 8; ++c) {
      const int idx = c * 256 + tid;
      const int row = idx >> 4;
      const int colc = (idx & 15) * 8;
      *(v8s*)&C[(unsigned long long)(m0 + row) * ldc + n0 + colc] =
          *(const v8s*)&Ct[row * ST + colc];
    }
  } else {
    float* Cf = (float*)smem;
    const int ST = 132;
    float* C = (float*)Cg;
#pragma unroll
    for (int h = 0; h < 2; ++h) {
      if (wr == h) {
#pragma unroll
        for (int i = 0; i < 4; ++i) {
          const int rl = i * 16 + rq;
#pragma unroll
          for (int j = 0; j < 4; ++j) {
            const int col = wc * 64 + j * 16 + cf;
#pragma unroll
            for (int r = 0; r < 4; ++r) Cf[(rl + r) * ST + col] = acc[i][j][r];
          }
        }
      }
      __syncthreads();
#pragma unroll
      for (int c = 0; c < 8; ++c) {
        const int idx = c * 256 + tid;
        const int row = idx >> 5;
        const int colc = (idx & 31) * 4;
        const int grow = m0 + h * 64 + row;
        const int gcol = n0 + colc;
        float4 v = *(const float4*)&Cf[row * ST + colc];
        float4 b4 = *(const float4*)&ep.bias[gcol];
        ushort4 r4 = *(const ushort4*)&ep.resid[(unsigned long long)grow * ep.resid_ld + gcol];
        v.x += b4.x + __bfloat162float(*(__hip_bfloat16*)&r4.x);
        v.y += b4.y + __bfloat162float(*(__hip_bfloat16*)&r4.y);
        v.z += b4.z + __bfloat162float(*(__hip_bfloat16*)&r4.z);
        v.w += b4.w + __bfloat162float(*(__hip_bfloat16*)&r4.w);
        *(float4*)&C[(unsigned long long)grow * ldc + gcol] = v;
      }
      if (h == 0) __syncthreads();
    }
  }
}

template <int EPI>
__global__ __launch_bounds__(256, 3) void gemm_bt(
    const __hip_bfloat16* __restrict__ Ag, const __hip_bfloat16* __restrict__ Bg,
    void* __restrict__ Cg, int K, int lda, int ldb, int ldc,
    unsigned long long sAz, unsigned long long sBz, unsigned long long sCz, EpiParams ep) {
  __shared__ __align__(16) unsigned char smem[SMEM_BYTES];
  const unsigned long long z = blockIdx.z;
  void* Cz;
  if constexpr (EPI == EPI_FINAL) Cz = (void*)((float*)Cg + z * sCz);
  else Cz = (void*)((__hip_bfloat16*)Cg + z * sCz);
  gemm_body<EPI, false, false>(Ag + z * sAz, Bg + z * sBz, Cz, K, lda, ldb, ldc,
                               blockIdx.y * 128, blockIdx.x * 128, ep, smem);
}

// q/k/v projections, one launch, cast fused into staging. grid = (128, 4, 3).
// z=0: q = Q @ Wq^T -> qb[s][f]      (A f32)
// z=1: k = K @ Wk^T -> kb[s][f]      (A f32)
// z=2: v^T = Wv @ K^T -> vT[e][s]    (B f32; bm=by over e, bn=bx over s)
__global__ __launch_bounds__(256, 3) void gemm_qkv(
    const float* __restrict__ Q, const float* __restrict__ K,
    const __hip_bfloat16* __restrict__ Wq, const __hip_bfloat16* __restrict__ Wk,
    const __hip_bfloat16* __restrict__ Wv,
    __hip_bfloat16* __restrict__ qb, __hip_bfloat16* __restrict__ kb,
    __hip_bfloat16* __restrict__ vT) {
  __shared__ __align__(16) unsigned char smem[SMEM_BYTES];
  const int z = blockIdx.z;
  EpiParams ep{};
  if (z == 2) {
    gemm_body<EPI_BF16, false, true>(Wv, K, vT, EE, EE, EE, BB * SS,
                                     blockIdx.y * 128, blockIdx.x * 128, ep, smem);
  } else {
    const float* A = (z == 0) ? Q : K;
    const __hip_bfloat16* B = (z == 0) ? Wq : Wk;
    __hip_bfloat16* C = (z == 0) ? qb : kb;
    gemm_body<EPI_BF16, true, false>(A, B, C, EE, EE, EE, EE,
                                     blockIdx.x * 128, blockIdx.y * 128, ep, smem);
  }
}

// ---------------- masked softmax ----------------
__global__ __launch_bounds__(256) void softmax_rows(__hip_bfloat16* __restrict__ sc,
                                                    const unsigned char* __restrict__ mask) {
  const unsigned long long row = blockIdx.x;
  __hip_bfloat16* p = sc + row * (unsigned long long)SS;
  const int tid = threadIdx.x;
  const int lane = tid & 63;
  const int wv = tid >> 6;

  alignas(16) __hip_bfloat16 hv[8];
  ((uint4*)hv)[0] = *(const uint4*)&p[tid * 8];
  const unsigned long long mbits =
      *(const unsigned long long*)(mask + row * (unsigned long long)SS + tid * 8);

  float v[8];
  float m = -3.4e38f;
#pragma unroll
  for (int i = 0; i < 8; ++i) {
    v[i] = ((mbits >> (8 * i)) & 0xffull) ? -1e9f : __bfloat162float(hv[i]);
    m = fmaxf(m, v[i]);
  }
#pragma unroll
  for (int off = 32; off >= 1; off >>= 1) m = fmaxf(m, __shfl_xor(m, off));

  __shared__ float redm[4];
  __shared__ float reds[4];
  if (lane == 0) redm[wv] = m;
  __syncthreads();
  m = fmaxf(fmaxf(redm[0], redm[1]), fmaxf(redm[2], redm[3]));

  float s = 0.f;
#pragma unroll
  for (int i = 0; i < 8; ++i) {
    v[i] = __expf(v[i] - m);
    s += v[i];
  }
#pragma unroll
  for (int off = 32; off >= 1; off >>= 1) s += __shfl_xor(s, off);
  if (lane == 0) reds[wv] = s;
  __syncthreads();
  s = reds[0] + reds[1] + reds[2] + reds[3];
  const float inv = 1.0f / s;

#pragma unroll
  for (int i = 0; i < 8; ++i) hv[i] = __float2bfloat16(v[i] * inv);
  *(uint4*)&p[tid * 8] = ((uint4*)hv)[0];
}

extern "C" void kernel_launch(void* const* d_in, const int* in_sizes, int n_in,
                              void* d_out, int out_size, void* d_ws, size_t ws_size,
                              hipStream_t stream) {
  const float* Q = (const float*)d_in[0];
  const float* K = (const float*)d_in[1];
  const unsigned char* mask = (const unsigned char*)d_in[2];  // numpy bool, 1 byte
  const float* Wq = (const float*)d_in[3];
  const float* Wk = (const float*)d_in[4];
  const float* Wv = (const float*)d_in[5];
  const float* Wp = (const float*)d_in[6];
  const float* bp = (const float*)d_in[7];
  float* out = (float*)d_out;

  // Workspace (lifetime-aliased):
  //   [0,16)   qb [B*S,E]; lives to final epilogue (residual)
  //   [16,32)  kb [B*S,E]; dead after scores -> reused as ob [B*S,E]
  //   [32,48)  vT [E,B*S]
  //   [48,50)  Wqb,Wkb,Wvb,Wpb
  //   [64,128) sc [B,S,S]
  char* ws = (char*)d_ws;
  const unsigned long long MB = 1024ull * 1024ull;
  __hip_bfloat16* qb = (__hip_bfloat16*)(ws + 0 * MB);
  __hip_bfloat16* kb = (__hip_bfloat16*)(ws + 16 * MB);
  __hip_bfloat16* ob = kb;  // alias, disjoint lifetime
  __hip_bfloat16* vT = (__hip_bfloat16*)(ws + 32 * MB);
  __hip_bfloat16* Wqb = (__hip_bfloat16*)(ws + 48 * MB);
  __hip_bfloat16* Wkb = Wqb + 512 * 512;
  __hip_bfloat16* Wvb = Wkb + 512 * 512;
  __hip_bfloat16* Wpb = Wvb + 512 * 512;
  __hip_bfloat16* sc = (__hip_bfloat16*)(ws + 64 * MB);

  dim3 blk(256, 1, 1);

  // 1) weights cast (tiny: 4 MB)
  CastParams cp;
  cp.src[0] = Wq; cp.dst[0] = Wqb;
  cp.src[1] = Wk; cp.dst[1] = Wkb;
  cp.src[2] = Wv; cp.dst[2] = Wvb;
  cp.src[3] = Wp; cp.dst[3] = Wpb;
  cast_weights<<<dim3(512, 1, 1), blk, 0, stream>>>(cp);

  // 2) q/k/v projections with fused input cast
  gemm_qkv<<<dim3((BB * SS) / 128, EE / 128, 3), blk, 0, stream>>>(
      Q, K, Wqb, Wkb, Wvb, qb, kb, vT);

  // 3) scores[b] = (q_b @ k_b^T) * scale -> sc[q][k] bf16 (mask in softmax)
  EpiParams eps{};
  eps.scale = 0.044194173824159216f;  // 512^-0.5
  gemm_bt<EPI_SCALE><<<dim3(SS / 128, SS / 128, BB), blk, 0, stream>>>(
      qb, kb, sc, EE, EE, EE, SS,
      (unsigned long long)SS * EE, (unsigned long long)SS * EE,
      (unsigned long long)SS * SS, eps);

  // 4) masked softmax rows, in place
  softmax_rows<<<dim3(BB * SS, 1, 1), blk, 0, stream>>>(sc, mask);

  // 5) ob[b] = P_b @ v_b : A=sc (lda=S), B=vT rows=e (ldb=B*S, batch offset S)
  EpiParams ep0{};
  gemm_bt<EPI_BF16><<<dim3(EE / 128, SS / 128, BB), blk, 0, stream>>>(
      sc, vT, ob, SS, SS, BB * SS, EE,
      (unsigned long long)SS * SS, (unsigned long long)SS,
      (unsigned long long)SS * EE, ep0);

  // 6) out = q + (ob @ Wp^T + bp)  f32
  EpiParams epf{};
  epf.bias = bp;
  epf.resid = qb;
  epf.resid_ld = EE;
  gemm_bt<EPI_FINAL><<<dim3(EE / 128, (BB * SS) / 128, 1), blk, 0, stream>>>(
      ob, Wpb, out, EE, EE, EE, EE, 0ull, 0ull, 0ull, epf);
}